// Round 1
// baseline (464.763 us; speedup 1.0000x reference)
//
#include <hip/hip_runtime.h>

#define BB 4
#define NLAM 96
#define HH 256
#define WW 256
#define HO 288
#define WO 288
#define NK 4
#define KS 15
#define PADK 7

// ---------------------------------------------------------------------------
// Kernel 0: per-(k,lam) shift params.
// shifted[y,x] = padded[y-dy, x-dx] bilinear, zeros outside.
// In cube coords: fy = y - dy - 16 = y + sy, sy = -dy-16; oy=floor(sy), wy=frac.
// ---------------------------------------------------------------------------
__global__ __launch_bounds__(384) void params_k(const float* __restrict__ dx,
                                                const float* __restrict__ dy,
                                                float4* __restrict__ pw,
                                                int2* __restrict__ po) {
    int i = threadIdx.x;
    if (i < NK * NLAM) {
        float sx = -dx[i] - 16.0f;
        float sy = -dy[i] - 16.0f;
        float fx = floorf(sx), fy = floorf(sy);
        float wx = sx - fx, wy = sy - fy;
        po[i] = make_int2((int)fx, (int)fy);
        pw[i] = make_float4((1.0f - wy) * (1.0f - wx),
                            (1.0f - wy) * wx,
                            wy * (1.0f - wx),
                            wy * wx);
    }
}

// ---------------------------------------------------------------------------
// Kernel 1: shift + accumulate over lambda, all 4 k's per thread.
// acc[b][k][y][x] = sum_lam bilinear4tap(cube[b][lam], y+oy, x+ox)
// ---------------------------------------------------------------------------
__global__ __launch_bounds__(256) void shift_accum(const float* __restrict__ cube,
                                                   const float4* __restrict__ pw,
                                                   const int2* __restrict__ po,
                                                   float* __restrict__ acc) {
    const int b   = blockIdx.z;
    const int tx0 = blockIdx.x * 32;
    const int ty0 = blockIdx.y * 8;
    const int x   = tx0 + threadIdx.x;
    const int y   = ty0 + threadIdx.y;
    const float* __restrict__ cb = cube + (size_t)b * NLAM * HH * WW;

    float a0 = 0.f, a1 = 0.f, a2 = 0.f, a3 = 0.f;

    for (int lam = 0; lam < NLAM; ++lam) {
        const float* __restrict__ img = cb + lam * (HH * WW);
#pragma unroll
        for (int k = 0; k < NK; ++k) {
            const int i = k * NLAM + lam;       // uniform index -> scalar loads
            const int2 o = po[i];
            const float4 w = pw[i];
            const int ix = x + o.x;
            const int iy = y + o.y;
            // block-uniform safety: whole tile (incl. +1 taps) inside [0,256)^2
            const bool safe = (tx0 + o.x >= 0) && (tx0 + o.x <= WW - 33) &&
                              (ty0 + o.y >= 0) && (ty0 + o.y <= HH - 9);
            float v;
            if (safe) {
                const float* p = img + iy * WW + ix;
                v = w.x * p[0] + w.y * p[1] + w.z * p[WW] + w.w * p[WW + 1];
            } else {
                const bool vy0 = (unsigned)iy       < (unsigned)HH;
                const bool vy1 = (unsigned)(iy + 1) < (unsigned)HH;
                const bool vx0 = (unsigned)ix       < (unsigned)WW;
                const bool vx1 = (unsigned)(ix + 1) < (unsigned)WW;
                float t00 = (vy0 && vx0) ? img[iy * WW + ix]           : 0.f;
                float t01 = (vy0 && vx1) ? img[iy * WW + ix + 1]       : 0.f;
                float t10 = (vy1 && vx0) ? img[(iy + 1) * WW + ix]     : 0.f;
                float t11 = (vy1 && vx1) ? img[(iy + 1) * WW + ix + 1] : 0.f;
                v = w.x * t00 + w.y * t01 + w.z * t10 + w.w * t11;
            }
            if (k == 0) a0 += v; else if (k == 1) a1 += v;
            else if (k == 2) a2 += v; else a3 += v;
        }
    }
    const size_t hw = (size_t)HO * WO;
    size_t base = ((size_t)(b * NK) * HO + y) * WO + x;
    acc[base]          = a0;
    acc[base + hw]     = a1;
    acc[base + 2 * hw] = a2;
    acc[base + 3 * hw] = a3;
}

// ---------------------------------------------------------------------------
// Kernel 2: 15x15 PSF correlation, zero-padded "same".
// Block: 64x4 threads; each thread computes a 4-row column of outputs.
// LDS tile: 30 rows x 78 cols (16+14 x 64+14).
// ---------------------------------------------------------------------------
__global__ __launch_bounds__(256) void conv_psf(const float* __restrict__ acc,
                                                const float* __restrict__ psf,
                                                float* __restrict__ out) {
    __shared__ float tile[30][78];
    const int bk  = blockIdx.z;               // b*4 + k
    const int gx0 = blockIdx.x * 64 - PADK;
    const int gy0 = blockIdx.y * 16 - PADK;
    const float* __restrict__ ap = acc + (size_t)bk * HO * WO;

    const int tid = threadIdx.y * 64 + threadIdx.x;
    for (int i = tid; i < 30 * 78; i += 256) {
        int r = i / 78, c = i - r * 78;
        int gy = gy0 + r, gx = gx0 + c;
        tile[r][c] = ((unsigned)gy < (unsigned)HO && (unsigned)gx < (unsigned)WO)
                         ? ap[gy * WO + gx] : 0.f;
    }
    __syncthreads();

    const int tx = threadIdx.x;
    const int oy = threadIdx.y * 4;           // 0,4,8,12
    float o0 = 0.f, o1 = 0.f, o2 = 0.f, o3 = 0.f;
#pragma unroll
    for (int kx = 0; kx < KS; ++kx) {
        float r0 = tile[oy + 0][tx + kx];
        float r1 = tile[oy + 1][tx + kx];
        float r2 = tile[oy + 2][tx + kx];
#pragma unroll
        for (int ky = 0; ky < KS; ++ky) {
            float r3 = tile[oy + 3 + ky][tx + kx];
            float w  = psf[ky * KS + kx];     // uniform -> scalar load
            o0 += w * r0; o1 += w * r1; o2 += w * r2; o3 += w * r3;
            r0 = r1; r1 = r2; r2 = r3;
        }
    }

    const int x = blockIdx.x * 64 + tx;
    if (x < WO) {
        const int ybase = blockIdx.y * 16 + oy;
        float* op = out + ((size_t)bk * HO + ybase) * WO + x;
        op[0]      = o0;
        op[WO]     = o1;
        op[2 * WO] = o2;
        op[3 * WO] = o3;
    }
}

// ---------------------------------------------------------------------------
extern "C" void kernel_launch(void* const* d_in, const int* in_sizes, int n_in,
                              void* d_out, int out_size, void* d_ws, size_t ws_size,
                              hipStream_t stream) {
    const float* cube = (const float*)d_in[0];
    const float* dx   = (const float*)d_in[1];
    const float* dy   = (const float*)d_in[2];
    const float* psf  = (const float*)d_in[3];
    float* out = (float*)d_out;

    // ws layout: acc (B*4*288*288 f32) | pw (384 float4) | po (384 int2)
    float*  acc = (float*)d_ws;
    float4* pw  = (float4*)((char*)d_ws + (size_t)BB * NK * HO * WO * sizeof(float));
    int2*   po  = (int2*)((char*)pw + (size_t)NK * NLAM * sizeof(float4));

    params_k<<<1, 384, 0, stream>>>(dx, dy, pw, po);

    dim3 b1(32, 8);
    dim3 g1(WO / 32, HO / 8, BB);
    shift_accum<<<g1, b1, 0, stream>>>(cube, pw, po, acc);

    dim3 b2(64, 4);
    dim3 g2((WO + 63) / 64, HO / 16, BB * NK);
    conv_psf<<<g2, b2, 0, stream>>>(acc, psf, out);
}

// Round 2
// 458.705 us; speedup vs baseline: 1.0132x; 1.0132x over previous
//
#include <hip/hip_runtime.h>

#define BB 4
#define NLAM 96
#define HH 256
#define WW 256
#define HO 288
#define WO 288
#define NK 4
#define KS 15
#define PADK 7

// 4-float vector with only 4-byte alignment guarantee (unaligned global loads
// are supported on gfx9+; backend emits global_load_dwordx4).
typedef float f4 __attribute__((ext_vector_type(4), aligned(4)));

// ---------------------------------------------------------------------------
// Kernel 0: per-(k,lam) shift params, separable weights.
// pw = (wx0, wx1, wy0, wy1); po = (ox, oy); gmm = (minox, maxox, minoy, maxoy)
// ---------------------------------------------------------------------------
__global__ __launch_bounds__(384) void params_k(const float* __restrict__ dx,
                                                const float* __restrict__ dy,
                                                float4* __restrict__ pw,
                                                int2* __restrict__ po,
                                                int4* __restrict__ gmm) {
    __shared__ int s_minx, s_maxx, s_miny, s_maxy;
    const int i = threadIdx.x;
    if (i == 0) { s_minx = 1 << 30; s_maxx = -(1 << 30);
                  s_miny = 1 << 30; s_maxy = -(1 << 30); }
    __syncthreads();
    const float sx = -dx[i] - 16.0f;
    const float sy = -dy[i] - 16.0f;
    const float fx = floorf(sx), fy = floorf(sy);
    const int ox = (int)fx, oy = (int)fy;
    po[i] = make_int2(ox, oy);
    pw[i] = make_float4(1.0f - (sx - fx), sx - fx, 1.0f - (sy - fy), sy - fy);
    atomicMin(&s_minx, ox); atomicMax(&s_maxx, ox);
    atomicMin(&s_miny, oy); atomicMax(&s_maxy, oy);
    __syncthreads();
    if (i == 0) *gmm = make_int4(s_minx, s_maxx, s_miny, s_maxy);
}

// ---------------------------------------------------------------------------
// Kernel 1: shift + accumulate. Thread = 4 consecutive x outputs, 1 row.
// Block (8,8) = 1 wave covers 32x8 tile. Branch-free inner loops; block-level
// fast/edge selection from global offset min/max (uniform scalar branch).
// ---------------------------------------------------------------------------
#define FASTK(K, A) { \
    const int i_ = (K) * NLAM + lam; \
    const int2 o = po[i_]; const float4 w = pw[i_]; \
    const float* p = img + (y + o.y) * WW + (x + o.x); \
    const f4 r0 = *(const f4*)p;         const float r0e = p[4]; \
    const f4 r1 = *(const f4*)(p + WW);  const float r1e = p[WW + 4]; \
    const f4 rb = w.z * r0 + w.w * r1; \
    const float rbe = w.z * r0e + w.w * r1e; \
    A.x += w.x * rb.x + w.y * rb.y; \
    A.y += w.x * rb.y + w.y * rb.z; \
    A.z += w.x * rb.z + w.y * rb.w; \
    A.w += w.x * rb.w + w.y * rbe; }

#define EDGEK(K, A) { \
    const int i_ = (K) * NLAM + lam; \
    const int2 o = po[i_]; const float4 w = pw[i_]; \
    const int ix = x + o.x, iy = y + o.y; \
    const int cy0 = min(max(iy, 0), HH - 1); \
    const int cy1 = min(max(iy + 1, 0), HH - 1); \
    const float my0 = ((unsigned)iy       < (unsigned)HH) ? w.z : 0.0f; \
    const float my1 = ((unsigned)(iy + 1) < (unsigned)HH) ? w.w : 0.0f; \
    const float* r0p = img + cy0 * WW; \
    const float* r1p = img + cy1 * WW; \
    float rb[5]; \
    _Pragma("unroll") \
    for (int c = 0; c < 5; ++c) { \
        const int cx = min(max(ix + c, 0), WW - 1); \
        const float m = ((unsigned)(ix + c) < (unsigned)WW) ? 1.0f : 0.0f; \
        rb[c] = m * (my0 * r0p[cx] + my1 * r1p[cx]); \
    } \
    A.x += w.x * rb[0] + w.y * rb[1]; \
    A.y += w.x * rb[1] + w.y * rb[2]; \
    A.z += w.x * rb[2] + w.y * rb[3]; \
    A.w += w.x * rb[3] + w.y * rb[4]; }

__global__ __launch_bounds__(64) void shift_accum(const float* __restrict__ cube,
                                                  const float4* __restrict__ pw,
                                                  const int2* __restrict__ po,
                                                  const int4* __restrict__ gmm,
                                                  float* __restrict__ acc) {
    const int b   = blockIdx.z;
    const int tx0 = blockIdx.x * 32;
    const int ty0 = blockIdx.y * 8;
    const int x   = tx0 + threadIdx.x * 4;
    const int y   = ty0 + threadIdx.y;
    const float* __restrict__ cb = cube + (size_t)b * NLAM * HH * WW;

    const int4 mm = *gmm;   // uniform scalar load
    const bool fast = (tx0 + mm.x >= 0) && (tx0 + 31 + mm.y + 4 < WW) &&
                      (ty0 + mm.z >= 0) && (ty0 + 7 + mm.w + 1 < HH);

    f4 a0 = {0.f, 0.f, 0.f, 0.f};
    f4 a1 = {0.f, 0.f, 0.f, 0.f};
    f4 a2 = {0.f, 0.f, 0.f, 0.f};
    f4 a3 = {0.f, 0.f, 0.f, 0.f};

    if (fast) {
        for (int lam = 0; lam < NLAM; ++lam) {
            const float* __restrict__ img = cb + lam * (HH * WW);
            FASTK(0, a0) FASTK(1, a1) FASTK(2, a2) FASTK(3, a3)
        }
    } else {
        for (int lam = 0; lam < NLAM; ++lam) {
            const float* __restrict__ img = cb + lam * (HH * WW);
            EDGEK(0, a0) EDGEK(1, a1) EDGEK(2, a2) EDGEK(3, a3)
        }
    }

    const size_t hw = (size_t)HO * WO;
    const size_t base = ((size_t)(b * NK) * HO + y) * WO + x;  // 16B aligned
    *(f4*)(acc + base)          = a0;
    *(f4*)(acc + base + hw)     = a1;
    *(f4*)(acc + base + 2 * hw) = a2;
    *(f4*)(acc + base + 3 * hw) = a3;
}

// ---------------------------------------------------------------------------
// Kernel 2: 15x15 PSF correlation, zero-padded "same". (unchanged)
// ---------------------------------------------------------------------------
__global__ __launch_bounds__(256) void conv_psf(const float* __restrict__ acc,
                                                const float* __restrict__ psf,
                                                float* __restrict__ out) {
    __shared__ float tile[30][78];
    const int bk  = blockIdx.z;               // b*4 + k
    const int gx0 = blockIdx.x * 64 - PADK;
    const int gy0 = blockIdx.y * 16 - PADK;
    const float* __restrict__ ap = acc + (size_t)bk * HO * WO;

    const int tid = threadIdx.y * 64 + threadIdx.x;
    for (int i = tid; i < 30 * 78; i += 256) {
        int r = i / 78, c = i - r * 78;
        int gy = gy0 + r, gx = gx0 + c;
        tile[r][c] = ((unsigned)gy < (unsigned)HO && (unsigned)gx < (unsigned)WO)
                         ? ap[gy * WO + gx] : 0.f;
    }
    __syncthreads();

    const int tx = threadIdx.x;
    const int oy = threadIdx.y * 4;           // 0,4,8,12
    float o0 = 0.f, o1 = 0.f, o2 = 0.f, o3 = 0.f;
#pragma unroll
    for (int kx = 0; kx < KS; ++kx) {
        float r0 = tile[oy + 0][tx + kx];
        float r1 = tile[oy + 1][tx + kx];
        float r2 = tile[oy + 2][tx + kx];
#pragma unroll
        for (int ky = 0; ky < KS; ++ky) {
            float r3 = tile[oy + 3 + ky][tx + kx];
            float w  = psf[ky * KS + kx];     // uniform -> scalar load
            o0 += w * r0; o1 += w * r1; o2 += w * r2; o3 += w * r3;
            r0 = r1; r1 = r2; r2 = r3;
        }
    }

    const int x = blockIdx.x * 64 + tx;
    if (x < WO) {
        const int ybase = blockIdx.y * 16 + oy;
        float* op = out + ((size_t)bk * HO + ybase) * WO + x;
        op[0]      = o0;
        op[WO]     = o1;
        op[2 * WO] = o2;
        op[3 * WO] = o3;
    }
}

// ---------------------------------------------------------------------------
extern "C" void kernel_launch(void* const* d_in, const int* in_sizes, int n_in,
                              void* d_out, int out_size, void* d_ws, size_t ws_size,
                              hipStream_t stream) {
    const float* cube = (const float*)d_in[0];
    const float* dx   = (const float*)d_in[1];
    const float* dy   = (const float*)d_in[2];
    const float* psf  = (const float*)d_in[3];
    float* out = (float*)d_out;

    // ws layout: acc | pw | po | gmm
    float*  acc = (float*)d_ws;
    float4* pw  = (float4*)((char*)d_ws + (size_t)BB * NK * HO * WO * sizeof(float));
    int2*   po  = (int2*)((char*)pw + (size_t)NK * NLAM * sizeof(float4));
    int4*   gmm = (int4*)((char*)po + (size_t)NK * NLAM * sizeof(int2));

    params_k<<<1, 384, 0, stream>>>(dx, dy, pw, po, gmm);

    dim3 b1(8, 8);
    dim3 g1(WO / 32, HO / 8, BB);
    shift_accum<<<g1, b1, 0, stream>>>(cube, pw, po, gmm, acc);

    dim3 b2(64, 4);
    dim3 g2((WO + 63) / 64, HO / 16, BB * NK);
    conv_psf<<<g2, b2, 0, stream>>>(acc, psf, out);
}

// Round 3
// 361.596 us; speedup vs baseline: 1.2853x; 1.2686x over previous
//
#include <hip/hip_runtime.h>

#define BB 4
#define NLAM 96
#define HH 256
#define WW 256
#define HO 288
#define WO 288
#define NK 4
#define KS 15
#define PADK 7

#define ACC_N ((size_t)BB * NK * HO * WO)   // floats in one acc image set

typedef float f4 __attribute__((ext_vector_type(4), aligned(4)));
typedef float f4a __attribute__((ext_vector_type(4)));  // 16B aligned

// ---------------------------------------------------------------------------
// Kernel 0: per-(k,lam) shift params, separable weights.
// pw = (wx0, wx1, wy0, wy1); po = (ox, oy); gmm = (minox, maxox, minoy, maxoy)
// ---------------------------------------------------------------------------
__global__ __launch_bounds__(384) void params_k(const float* __restrict__ dx,
                                                const float* __restrict__ dy,
                                                float4* __restrict__ pw,
                                                int2* __restrict__ po,
                                                int4* __restrict__ gmm) {
    __shared__ int s_minx, s_maxx, s_miny, s_maxy;
    const int i = threadIdx.x;
    if (i == 0) { s_minx = 1 << 30; s_maxx = -(1 << 30);
                  s_miny = 1 << 30; s_maxy = -(1 << 30); }
    __syncthreads();
    const float sx = -dx[i] - 16.0f;
    const float sy = -dy[i] - 16.0f;
    const float fx = floorf(sx), fy = floorf(sy);
    const int ox = (int)fx, oy = (int)fy;
    po[i] = make_int2(ox, oy);
    pw[i] = make_float4(1.0f - (sx - fx), sx - fx, 1.0f - (sy - fy), sy - fy);
    atomicMin(&s_minx, ox); atomicMax(&s_maxx, ox);
    atomicMin(&s_miny, oy); atomicMax(&s_maxy, oy);
    __syncthreads();
    if (i == 0) *gmm = make_int4(s_minx, s_maxx, s_miny, s_maxy);
}

// ---------------------------------------------------------------------------
// Kernel 1: shift + accumulate over a lambda CHUNK; grid.z = BB * S.
// Thread = 4 consecutive x outputs, 1 row. Block (8,32) = 4 waves, 32x32 tile.
// Partials: part[c] is a full (B,4,288,288) slice; reduced later.
// ---------------------------------------------------------------------------
#define FASTK(K, A) { \
    const int i_ = (K) * NLAM + lam; \
    const int2 o = po[i_]; const float4 w = pw[i_]; \
    const float* p = img + (y + o.y) * WW + (x + o.x); \
    const f4 r0 = *(const f4*)p;         const float r0e = p[4]; \
    const f4 r1 = *(const f4*)(p + WW);  const float r1e = p[WW + 4]; \
    const f4 rb = w.z * r0 + w.w * r1; \
    const float rbe = w.z * r0e + w.w * r1e; \
    A.x += w.x * rb.x + w.y * rb.y; \
    A.y += w.x * rb.y + w.y * rb.z; \
    A.z += w.x * rb.z + w.y * rb.w; \
    A.w += w.x * rb.w + w.y * rbe; }

#define EDGEK(K, A) { \
    const int i_ = (K) * NLAM + lam; \
    const int2 o = po[i_]; const float4 w = pw[i_]; \
    const int ix = x + o.x, iy = y + o.y; \
    const int cy0 = min(max(iy, 0), HH - 1); \
    const int cy1 = min(max(iy + 1, 0), HH - 1); \
    const float my0 = ((unsigned)iy       < (unsigned)HH) ? w.z : 0.0f; \
    const float my1 = ((unsigned)(iy + 1) < (unsigned)HH) ? w.w : 0.0f; \
    const float* r0p = img + cy0 * WW; \
    const float* r1p = img + cy1 * WW; \
    float rb[5]; \
    _Pragma("unroll") \
    for (int c = 0; c < 5; ++c) { \
        const int cx = min(max(ix + c, 0), WW - 1); \
        const float m = ((unsigned)(ix + c) < (unsigned)WW) ? 1.0f : 0.0f; \
        rb[c] = m * (my0 * r0p[cx] + my1 * r1p[cx]); \
    } \
    A.x += w.x * rb[0] + w.y * rb[1]; \
    A.y += w.x * rb[1] + w.y * rb[2]; \
    A.z += w.x * rb[2] + w.y * rb[3]; \
    A.w += w.x * rb[3] + w.y * rb[4]; }

__global__ __launch_bounds__(256) void shift_accum(const float* __restrict__ cube,
                                                   const float4* __restrict__ pw,
                                                   const int2* __restrict__ po,
                                                   const int4* __restrict__ gmm,
                                                   float* __restrict__ part,
                                                   int S, int chunk) {
    const int zc  = blockIdx.z;
    const int b   = zc / S;
    const int c   = zc - b * S;
    const int tx0 = blockIdx.x * 32;
    const int ty0 = blockIdx.y * 32;
    const int x   = tx0 + threadIdx.x * 4;
    const int y   = ty0 + threadIdx.y;
    const float* __restrict__ cb = cube + (size_t)b * NLAM * HH * WW;

    const int4 mm = *gmm;   // uniform scalar load
    const bool fast = (tx0 + mm.x >= 0) && (tx0 + 28 + mm.y + 4 <= WW - 1) &&
                      (ty0 + mm.z >= 0) && (ty0 + 31 + mm.w + 1 <= HH - 1);

    f4 a0 = {0.f, 0.f, 0.f, 0.f};
    f4 a1 = {0.f, 0.f, 0.f, 0.f};
    f4 a2 = {0.f, 0.f, 0.f, 0.f};
    f4 a3 = {0.f, 0.f, 0.f, 0.f};

    const int l0 = c * chunk, l1 = l0 + chunk;
    if (fast) {
        for (int lam = l0; lam < l1; ++lam) {
            const float* __restrict__ img = cb + lam * (HH * WW);
            FASTK(0, a0) FASTK(1, a1) FASTK(2, a2) FASTK(3, a3)
        }
    } else {
        for (int lam = l0; lam < l1; ++lam) {
            const float* __restrict__ img = cb + lam * (HH * WW);
            EDGEK(0, a0) EDGEK(1, a1) EDGEK(2, a2) EDGEK(3, a3)
        }
    }

    const size_t hw = (size_t)HO * WO;
    float* pa = part + (size_t)c * ACC_N;
    const size_t base = ((size_t)(b * NK) * HO + y) * WO + x;  // 16B aligned
    *(f4a*)(pa + base)          = a0;
    *(f4a*)(pa + base + hw)     = a1;
    *(f4a*)(pa + base + 2 * hw) = a2;
    *(f4a*)(pa + base + 3 * hw) = a3;
}

// ---------------------------------------------------------------------------
// Kernel 1b: sum S partial acc slices -> final acc. Grid-stride over f4.
// ---------------------------------------------------------------------------
__global__ __launch_bounds__(256) void reduce_k(const float* __restrict__ part,
                                                float* __restrict__ acc, int S) {
    const size_t i = ((size_t)blockIdx.x * 256 + threadIdx.x) * 4;
    if (i < ACC_N) {
        f4a s = *(const f4a*)(part + i);
        for (int c = 1; c < S; ++c)
            s += *(const f4a*)(part + (size_t)c * ACC_N + i);
        *(f4a*)(acc + i) = s;
    }
}

// ---------------------------------------------------------------------------
// Kernel 2: 15x15 PSF correlation, zero-padded "same".
// Tile 96x32 outputs per block (exact tiling of 288), block (24,8) = 192 thr.
// Thread computes a 4x4 output block from a register 18-float row window.
// out[y][x] = sum_{ky,kx} psf[ky][kx] * acc[y-7+ky][x-7+kx]
// ---------------------------------------------------------------------------
#define TPX 112   // padded LDS row pitch (96 + 14 -> 110, pad to 112 for 16B)
__global__ __launch_bounds__(192) void conv_psf(const float* __restrict__ acc,
                                                const float* __restrict__ psf,
                                                float* __restrict__ out) {
    __shared__ float tile[46][TPX];
    const int bk  = blockIdx.z;               // b*4 + k
    const int gx0 = blockIdx.x * 96 - PADK;
    const int gy0 = blockIdx.y * 32 - PADK;
    const float* __restrict__ ap = acc + (size_t)bk * HO * WO;

    const int tid = threadIdx.y * 24 + threadIdx.x;   // 0..191
    for (int i = tid; i < 46 * 110; i += 192) {
        int r = i / 110, c = i - r * 110;
        int gy = gy0 + r, gx = gx0 + c;
        tile[r][c] = ((unsigned)gy < (unsigned)HO && (unsigned)gx < (unsigned)WO)
                         ? ap[gy * WO + gx] : 0.f;
    }
    __syncthreads();

    const int x0 = threadIdx.x * 4;   // 0..92
    const int y0 = threadIdx.y * 4;   // 0..28
    float o[4][4] = {};

    for (int rr = 0; rr < 18; ++rr) {         // input rows this thread touches
        const float* rp = &tile[y0 + rr][x0];
        float row[18];
#pragma unroll
        for (int q = 0; q < 4; ++q) {         // 16B-aligned LDS vector reads
            f4a v = *(const f4a*)(rp + 4 * q);
            row[4 * q]     = v.x; row[4 * q + 1] = v.y;
            row[4 * q + 2] = v.z; row[4 * q + 3] = v.w;
        }
        row[16] = rp[16]; row[17] = rp[17];

#pragma unroll
        for (int j = 0; j < 4; ++j) {
            const int ky = rr - j;
            if (ky >= 0 && ky < KS) {         // uniform branch (rr uniform)
                const float* w = psf + ky * KS;  // uniform -> scalar loads
#pragma unroll
                for (int kx = 0; kx < KS; ++kx) {
                    const float wv = w[kx];
#pragma unroll
                    for (int i = 0; i < 4; ++i) o[j][i] += wv * row[kx + i];
                }
            }
        }
    }

    const int xo = blockIdx.x * 96 + x0;
    const int yo = blockIdx.y * 32 + y0;
    float* op = out + ((size_t)bk * HO + yo) * WO + xo;
#pragma unroll
    for (int j = 0; j < 4; ++j) {
        f4a v = { o[j][0], o[j][1], o[j][2], o[j][3] };
        *(f4a*)(op + (size_t)j * WO) = v;
    }
}

// ---------------------------------------------------------------------------
extern "C" void kernel_launch(void* const* d_in, const int* in_sizes, int n_in,
                              void* d_out, int out_size, void* d_ws, size_t ws_size,
                              hipStream_t stream) {
    const float* cube = (const float*)d_in[0];
    const float* dx   = (const float*)d_in[1];
    const float* dy   = (const float*)d_in[2];
    const float* psf  = (const float*)d_in[3];
    float* out = (float*)d_out;

    const size_t ACCB   = ACC_N * sizeof(float);
    const size_t tables = 384 * sizeof(float4) + 384 * sizeof(int2) + sizeof(int4);

    // pick largest lambda-split that fits ws: need (S+1)*ACCB + tables
    int S = 1;
    for (int cand : {6, 3, 2}) {
        if (ws_size >= (size_t)(cand + 1) * ACCB + tables) { S = cand; break; }
    }
    const int chunk = NLAM / S;

    float* part = (float*)d_ws;
    float* acc  = (S > 1) ? part + (size_t)S * ACC_N : part;
    char*  tb   = (char*)d_ws + (size_t)(S > 1 ? S + 1 : 1) * ACCB;
    float4* pw  = (float4*)tb;
    int2*   po  = (int2*)(tb + 384 * sizeof(float4));
    int4*   gmm = (int4*)(tb + 384 * sizeof(float4) + 384 * sizeof(int2));

    params_k<<<1, 384, 0, stream>>>(dx, dy, pw, po, gmm);

    dim3 b1(8, 32);
    dim3 g1(WO / 32, HO / 32, BB * S);
    shift_accum<<<g1, b1, 0, stream>>>(cube, pw, po, gmm, part, S, chunk);

    if (S > 1) {
        const int nf4 = (int)(ACC_N / 4);                 // 331776
        reduce_k<<<(nf4 + 255) / 256, 256, 0, stream>>>(part, acc, S);
    }

    dim3 b2(24, 8);
    dim3 g2(WO / 96, HO / 32, BB * NK);
    conv_psf<<<g2, b2, 0, stream>>>(acc, psf, out);
}

// Round 4
// 281.129 us; speedup vs baseline: 1.6532x; 1.2862x over previous
//
#include <hip/hip_runtime.h>

#define BB 4
#define NLAM 96
#define HH 256
#define WW 256
#define HO 288
#define WO 288
#define NK 4
#define KS 15
#define PADK 7

#define ACC_N ((size_t)BB * NK * HO * WO)   // floats in one acc image set

// LDS staging tile for shift_accum: 64 rows x 68 cols, pitch 69 (odd ->
// stride-4 lane gathers hit <=2-way bank aliasing, which is free).
#define TR 64
#define TQ 17            // quads per row staged (68 cols)
#define TP 69            // row pitch in floats

typedef float f4 __attribute__((ext_vector_type(4), aligned(4)));
typedef float f4a __attribute__((ext_vector_type(4)));  // 16B aligned

// ---------------------------------------------------------------------------
// Kernel 0: per-(k,lam) shift params, separable weights.
// pw = (wx0, wx1, wy0, wy1); po = (ox, oy); gmm = (minox, maxox, minoy, maxoy)
// ---------------------------------------------------------------------------
__global__ __launch_bounds__(384) void params_k(const float* __restrict__ dx,
                                                const float* __restrict__ dy,
                                                float4* __restrict__ pw,
                                                int2* __restrict__ po,
                                                int4* __restrict__ gmm) {
    __shared__ int s_minx, s_maxx, s_miny, s_maxy;
    const int i = threadIdx.x;
    if (i == 0) { s_minx = 1 << 30; s_maxx = -(1 << 30);
                  s_miny = 1 << 30; s_maxy = -(1 << 30); }
    __syncthreads();
    const float sx = -dx[i] - 16.0f;
    const float sy = -dy[i] - 16.0f;
    const float fx = floorf(sx), fy = floorf(sy);
    const int ox = (int)fx, oy = (int)fy;
    po[i] = make_int2(ox, oy);
    pw[i] = make_float4(1.0f - (sx - fx), sx - fx, 1.0f - (sy - fy), sy - fy);
    atomicMin(&s_minx, ox); atomicMax(&s_maxx, ox);
    atomicMin(&s_miny, oy); atomicMax(&s_maxy, oy);
    __syncthreads();
    if (i == 0) *gmm = make_int4(s_minx, s_maxx, s_miny, s_maxy);
}

// ---------------------------------------------------------------------------
// Fallback global-gather macros (used only if offset span exceeds LDS tile).
// ---------------------------------------------------------------------------
#define FASTK(K, A) { \
    const int i_ = (K) * NLAM + lam; \
    const int2 o = po[i_]; const float4 w = pw[i_]; \
    const float* p = img + (y + o.y) * WW + (x + o.x); \
    const f4 r0 = *(const f4*)p;         const float r0e = p[4]; \
    const f4 r1 = *(const f4*)(p + WW);  const float r1e = p[WW + 4]; \
    const f4 rb = w.z * r0 + w.w * r1; \
    const float rbe = w.z * r0e + w.w * r1e; \
    A.x += w.x * rb.x + w.y * rb.y; \
    A.y += w.x * rb.y + w.y * rb.z; \
    A.z += w.x * rb.z + w.y * rb.w; \
    A.w += w.x * rb.w + w.y * rbe; }

#define EDGEK(K, A) { \
    const int i_ = (K) * NLAM + lam; \
    const int2 o = po[i_]; const float4 w = pw[i_]; \
    const int ix = x + o.x, iy = y + o.y; \
    const int cy0 = min(max(iy, 0), HH - 1); \
    const int cy1 = min(max(iy + 1, 0), HH - 1); \
    const float my0 = ((unsigned)iy       < (unsigned)HH) ? w.z : 0.0f; \
    const float my1 = ((unsigned)(iy + 1) < (unsigned)HH) ? w.w : 0.0f; \
    const float* r0p = img + cy0 * WW; \
    const float* r1p = img + cy1 * WW; \
    float rb[5]; \
    _Pragma("unroll") \
    for (int c = 0; c < 5; ++c) { \
        const int cx = min(max(ix + c, 0), WW - 1); \
        const float m = ((unsigned)(ix + c) < (unsigned)WW) ? 1.0f : 0.0f; \
        rb[c] = m * (my0 * r0p[cx] + my1 * r1p[cx]); \
    } \
    A.x += w.x * rb[0] + w.y * rb[1]; \
    A.y += w.x * rb[1] + w.y * rb[2]; \
    A.z += w.x * rb[2] + w.y * rb[3]; \
    A.w += w.x * rb[3] + w.y * rb[4]; }

// ---------------------------------------------------------------------------
// Kernel 1: shift + accumulate over a lambda CHUNK; grid.z = BB * S.
// Per lambda: stage 64x68 apron region (zero-filled OOB) into LDS with
// aligned coalesced float4 loads, then gather all 4 k's from LDS.
// Thread = 4 consecutive x outputs, 1 row. Block (8,32) = 4 waves, 32x32 tile.
// ---------------------------------------------------------------------------
__global__ __launch_bounds__(256) void shift_accum(const float* __restrict__ cube,
                                                   const float4* __restrict__ pw,
                                                   const int2* __restrict__ po,
                                                   const int4* __restrict__ gmm,
                                                   float* __restrict__ part,
                                                   int S, int chunk) {
    __shared__ float tile[TR * TP];
    const int zc  = blockIdx.z;
    const int b   = zc / S;
    const int c   = zc - b * S;
    const int tx0 = blockIdx.x * 32;
    const int ty0 = blockIdx.y * 32;
    const int x   = tx0 + threadIdx.x * 4;
    const int y   = ty0 + threadIdx.y;
    const int tid = threadIdx.y * 8 + threadIdx.x;
    const float* __restrict__ cb = cube + (size_t)b * NLAM * HH * WW;

    const int4 mm = *gmm;   // uniform scalar load
    const int spanX = mm.y - mm.x;
    const int spanY = mm.w - mm.z;
    const bool lds_ok = (spanX <= 32) && (spanY <= 31);   // grid-uniform

    f4 a0 = {0.f, 0.f, 0.f, 0.f};
    f4 a1 = {0.f, 0.f, 0.f, 0.f};
    f4 a2 = {0.f, 0.f, 0.f, 0.f};
    f4 a3 = {0.f, 0.f, 0.f, 0.f};

    const int l0 = c * chunk, l1 = l0 + chunk;

    if (lds_ok) {
        const int row0 = ty0 + mm.z;                 // first staged image row
        const int col0 = (tx0 + mm.x) & ~3;          // aligned first col
        // Per-k gather bases (uniform offsets; lane-varying parts added below)
        for (int lam = l0; lam < l1; ++lam) {
            const float* __restrict__ img = cb + lam * (HH * WW);
            // ---- stage 64 x 68 region, zero-filled outside image ----
            for (int q = tid; q < TR * TQ; q += 256) {
                const int r  = q / TQ;
                const int qi = q - r * TQ;
                const int gy = row0 + r;
                const int gc = col0 + qi * 4;
                f4a v = {0.f, 0.f, 0.f, 0.f};
                if ((unsigned)gy < (unsigned)HH) {
                    const float* rp = img + (gy << 8);
                    if ((unsigned)gc <= (unsigned)(WW - 4)) {
                        v = *(const f4a*)(rp + gc);
                    } else {
#pragma unroll
                        for (int e = 0; e < 4; ++e)
                            if ((unsigned)(gc + e) < (unsigned)WW) v[e] = rp[gc + e];
                    }
                }
                const int la = r * TP + qi * 4;
                tile[la]     = v.x; tile[la + 1] = v.y;
                tile[la + 2] = v.z; tile[la + 3] = v.w;
            }
            __syncthreads();
            // ---- gather 4 k's from LDS ----
#pragma unroll
            for (int k = 0; k < NK; ++k) {
                const int i_ = k * NLAM + lam;
                const int2 o = po[i_]; const float4 w = pw[i_];
                const int lr = (y + o.y) - row0;
                const int lc = (x + o.x) - col0;
                const float* t0 = &tile[lr * TP + lc];
                float rb[5];
#pragma unroll
                for (int cc = 0; cc < 5; ++cc)
                    rb[cc] = w.z * t0[cc] + w.w * t0[TP + cc];
                f4 add;
                add.x = w.x * rb[0] + w.y * rb[1];
                add.y = w.x * rb[1] + w.y * rb[2];
                add.z = w.x * rb[2] + w.y * rb[3];
                add.w = w.x * rb[3] + w.y * rb[4];
                if (k == 0) a0 += add; else if (k == 1) a1 += add;
                else if (k == 2) a2 += add; else a3 += add;
            }
            __syncthreads();
        }
    } else {
        // fallback: original global-gather path
        const bool fast = (tx0 + mm.x >= 0) && (tx0 + 28 + mm.y + 4 <= WW - 1) &&
                          (ty0 + mm.z >= 0) && (ty0 + 31 + mm.w + 1 <= HH - 1);
        if (fast) {
            for (int lam = l0; lam < l1; ++lam) {
                const float* __restrict__ img = cb + lam * (HH * WW);
                FASTK(0, a0) FASTK(1, a1) FASTK(2, a2) FASTK(3, a3)
            }
        } else {
            for (int lam = l0; lam < l1; ++lam) {
                const float* __restrict__ img = cb + lam * (HH * WW);
                EDGEK(0, a0) EDGEK(1, a1) EDGEK(2, a2) EDGEK(3, a3)
            }
        }
    }

    const size_t hw = (size_t)HO * WO;
    float* pa = part + (size_t)c * ACC_N;
    const size_t base = ((size_t)(b * NK) * HO + y) * WO + x;  // 16B aligned
    *(f4a*)(pa + base)          = a0;
    *(f4a*)(pa + base + hw)     = a1;
    *(f4a*)(pa + base + 2 * hw) = a2;
    *(f4a*)(pa + base + 3 * hw) = a3;
}

// ---------------------------------------------------------------------------
// Kernel 1b: sum S partial acc slices -> final acc. Grid-stride over f4.
// ---------------------------------------------------------------------------
__global__ __launch_bounds__(256) void reduce_k(const float* __restrict__ part,
                                                float* __restrict__ acc, int S) {
    const size_t i = ((size_t)blockIdx.x * 256 + threadIdx.x) * 4;
    if (i < ACC_N) {
        f4a s = *(const f4a*)(part + i);
        for (int c = 1; c < S; ++c)
            s += *(const f4a*)(part + (size_t)c * ACC_N + i);
        *(f4a*)(acc + i) = s;
    }
}

// ---------------------------------------------------------------------------
// Kernel 2: 15x15 PSF correlation, zero-padded "same".
// Tile 96x32 outputs per block, block (24,8) = 192 thr, 4x4 outputs/thread.
// ---------------------------------------------------------------------------
#define TPX 112   // padded LDS row pitch
__global__ __launch_bounds__(192) void conv_psf(const float* __restrict__ acc,
                                                const float* __restrict__ psf,
                                                float* __restrict__ out) {
    __shared__ float tile[46][TPX];
    const int bk  = blockIdx.z;               // b*4 + k
    const int gx0 = blockIdx.x * 96 - PADK;
    const int gy0 = blockIdx.y * 32 - PADK;
    const float* __restrict__ ap = acc + (size_t)bk * HO * WO;

    const int tid = threadIdx.y * 24 + threadIdx.x;   // 0..191
    for (int i = tid; i < 46 * 110; i += 192) {
        int r = i / 110, c = i - r * 110;
        int gy = gy0 + r, gx = gx0 + c;
        tile[r][c] = ((unsigned)gy < (unsigned)HO && (unsigned)gx < (unsigned)WO)
                         ? ap[gy * WO + gx] : 0.f;
    }
    __syncthreads();

    const int x0 = threadIdx.x * 4;   // 0..92
    const int y0 = threadIdx.y * 4;   // 0..28
    float o[4][4] = {};

    for (int rr = 0; rr < 18; ++rr) {
        const float* rp = &tile[y0 + rr][x0];
        float row[18];
#pragma unroll
        for (int q = 0; q < 4; ++q) {
            f4a v = *(const f4a*)(rp + 4 * q);
            row[4 * q]     = v.x; row[4 * q + 1] = v.y;
            row[4 * q + 2] = v.z; row[4 * q + 3] = v.w;
        }
        row[16] = rp[16]; row[17] = rp[17];

#pragma unroll
        for (int j = 0; j < 4; ++j) {
            const int ky = rr - j;
            if (ky >= 0 && ky < KS) {
                const float* w = psf + ky * KS;
#pragma unroll
                for (int kx = 0; kx < KS; ++kx) {
                    const float wv = w[kx];
#pragma unroll
                    for (int i = 0; i < 4; ++i) o[j][i] += wv * row[kx + i];
                }
            }
        }
    }

    const int xo = blockIdx.x * 96 + x0;
    const int yo = blockIdx.y * 32 + y0;
    float* op = out + ((size_t)bk * HO + yo) * WO + xo;
#pragma unroll
    for (int j = 0; j < 4; ++j) {
        f4a v = { o[j][0], o[j][1], o[j][2], o[j][3] };
        *(f4a*)(op + (size_t)j * WO) = v;
    }
}

// ---------------------------------------------------------------------------
extern "C" void kernel_launch(void* const* d_in, const int* in_sizes, int n_in,
                              void* d_out, int out_size, void* d_ws, size_t ws_size,
                              hipStream_t stream) {
    const float* cube = (const float*)d_in[0];
    const float* dx   = (const float*)d_in[1];
    const float* dy   = (const float*)d_in[2];
    const float* psf  = (const float*)d_in[3];
    float* out = (float*)d_out;

    const size_t ACCB   = ACC_N * sizeof(float);
    const size_t tables = 384 * sizeof(float4) + 384 * sizeof(int2) + sizeof(int4);

    int S = 1;
    for (int cand : {6, 3, 2}) {
        if (ws_size >= (size_t)(cand + 1) * ACCB + tables) { S = cand; break; }
    }
    const int chunk = NLAM / S;

    float* part = (float*)d_ws;
    float* acc  = (S > 1) ? part + (size_t)S * ACC_N : part;
    char*  tb   = (char*)d_ws + (size_t)(S > 1 ? S + 1 : 1) * ACCB;
    float4* pw  = (float4*)tb;
    int2*   po  = (int2*)(tb + 384 * sizeof(float4));
    int4*   gmm = (int4*)(tb + 384 * sizeof(float4) + 384 * sizeof(int2));

    params_k<<<1, 384, 0, stream>>>(dx, dy, pw, po, gmm);

    dim3 b1(8, 32);
    dim3 g1(WO / 32, HO / 32, BB * S);
    shift_accum<<<g1, b1, 0, stream>>>(cube, pw, po, gmm, part, S, chunk);

    if (S > 1) {
        const int nf4 = (int)(ACC_N / 4);
        reduce_k<<<(nf4 + 255) / 256, 256, 0, stream>>>(part, acc, S);
    }

    dim3 b2(24, 8);
    dim3 g2(WO / 96, HO / 32, BB * NK);
    conv_psf<<<g2, b2, 0, stream>>>(acc, psf, out);
}

// Round 5
// 269.637 us; speedup vs baseline: 1.7237x; 1.0426x over previous
//
#include <hip/hip_runtime.h>

#define BB 4
#define NLAM 96
#define HH 256
#define WW 256
#define HO 288
#define WO 288
#define NK 4
#define KS 15
#define PADK 7

#define ACC_N ((size_t)BB * NK * HO * WO)   // floats in one partial slice

// shift_accum LDS tile: up to 65 rows x 104 data cols, pitch 105 (odd ->
// stride-4 gathers and row-strided access stay <=2-way on 32 banks).
#define SP 105
#define SROWS 65
#define SQUADS 26          // 26 quads = 104 cols capacity

typedef float f4 __attribute__((ext_vector_type(4), aligned(4)));
typedef float f4a __attribute__((ext_vector_type(4)));  // 16B aligned

// ---------------------------------------------------------------------------
// Kernel 0: per-(k,lam) shift params + offset min/max via shuffle reduction.
// pw = (wx0, wx1, wy0, wy1); po = (ox, oy); gmm = (minox, maxox, minoy, maxoy)
// ---------------------------------------------------------------------------
__global__ __launch_bounds__(384) void params_k(const float* __restrict__ dx,
                                                const float* __restrict__ dy,
                                                float4* __restrict__ pw,
                                                int2* __restrict__ po,
                                                int4* __restrict__ gmm) {
    __shared__ int sox[384], soy[384];
    const int i = threadIdx.x;
    const float sx = -dx[i] - 16.0f;
    const float sy = -dy[i] - 16.0f;
    const float fx = floorf(sx), fy = floorf(sy);
    const int ox = (int)fx, oy = (int)fy;
    po[i] = make_int2(ox, oy);
    pw[i] = make_float4(1.0f - (sx - fx), sx - fx, 1.0f - (sy - fy), sy - fy);
    sox[i] = ox; soy[i] = oy;
    __syncthreads();
    if (i < 64) {
        int mnx = sox[i], mxx = mnx, mny = soy[i], mxy = mny;
        for (int j = i + 64; j < 384; j += 64) {
            mnx = min(mnx, sox[j]); mxx = max(mxx, sox[j]);
            mny = min(mny, soy[j]); mxy = max(mxy, soy[j]);
        }
        for (int m = 32; m; m >>= 1) {
            mnx = min(mnx, __shfl_xor(mnx, m, 64));
            mxx = max(mxx, __shfl_xor(mxx, m, 64));
            mny = min(mny, __shfl_xor(mny, m, 64));
            mxy = max(mxy, __shfl_xor(mxy, m, 64));
        }
        if (i == 0) *gmm = make_int4(mnx, mxx, mny, mxy);
    }
}

// ---------------------------------------------------------------------------
// Kernel 1: shift + accumulate over a lambda chunk; grid.z = BB * S.
// Block (16,16) covers a 64x32 output tile; thread = 4x2 outputs per k.
// Per lambda: stage apron region into LDS (zero-filled OOB), gather 4 k's.
// ---------------------------------------------------------------------------
__global__ __launch_bounds__(256, 4) void shift_accum(
        const float* __restrict__ cube,
        const float4* __restrict__ pw,
        const int2* __restrict__ po,
        const int4* __restrict__ gmm,
        float* __restrict__ part,
        int S, int chunk) {
    __shared__ float tile[SROWS * SP];
    const int zc  = blockIdx.z;
    const int b   = zc / S;
    const int c   = zc - b * S;
    const int tx0 = blockIdx.x * 64;
    const int ty0 = blockIdx.y * 32;
    const int tx  = threadIdx.x, ty = threadIdx.y;
    const int x   = tx0 + tx * 4;
    const int y   = ty0 + ty * 2;
    const int tid = ty * 16 + tx;
    const float* __restrict__ cb = cube + (size_t)b * NLAM * HH * WW;

    const int4 mm = *gmm;   // uniform scalar load
    const int spanX = mm.y - mm.x;
    const int spanY = mm.w - mm.z;
    const bool lds_ok = (spanX <= 32) && (spanY <= 31);   // grid-uniform

    f4 a[NK][2];
#pragma unroll
    for (int k = 0; k < NK; ++k) { a[k][0] = (f4)0.f; a[k][1] = (f4)0.f; }

    const int l0 = c * chunk;
    const int l1 = min(NLAM, l0 + chunk);

    if (lds_ok) {
        const int row0 = ty0 + mm.z;
        const int col0 = (tx0 + mm.x) & ~3;
        const int R    = spanY + 34;              // staged rows, <= 65
        const int lrb  = ty * 2 - mm.z;           // + o.y = gather row
        const int lcb  = tx * 4 + (tx0 - col0);   // + o.x = gather col

        for (int lam = l0; lam < l1; ++lam) {
            const float* __restrict__ img = cb + lam * (HH * WW);
            // ---- stage R x 104 region, zero-filled outside image ----
            for (int q = tid; q < R * SQUADS; q += 256) {
                const int r  = q / SQUADS;
                const int qi = q - r * SQUADS;
                const int gy = row0 + r;
                const int gc = col0 + qi * 4;
                f4a v = {0.f, 0.f, 0.f, 0.f};
                if ((unsigned)gy < (unsigned)HH) {
                    const float* rp = img + (gy << 8);
                    if ((unsigned)gc <= (unsigned)(WW - 4)) {
                        v = *(const f4a*)(rp + gc);
                    } else {
#pragma unroll
                        for (int e = 0; e < 4; ++e)
                            if ((unsigned)(gc + e) < (unsigned)WW) v[e] = rp[gc + e];
                    }
                }
                const int la = r * SP + qi * 4;
                tile[la]     = v.x; tile[la + 1] = v.y;
                tile[la + 2] = v.z; tile[la + 3] = v.w;
            }
            __syncthreads();
            // ---- gather 4 k's: 3 rows x 5 cols each, 2 output rows ----
#pragma unroll
            for (int k = 0; k < NK; ++k) {
                const int i_ = k * NLAM + lam;
                const int2 o = po[i_]; const float4 w = pw[i_];
                const float* t = &tile[(lrb + o.y) * SP + (lcb + o.x)];
                float t0[5], t1[5], t2[5];
#pragma unroll
                for (int cc = 0; cc < 5; ++cc) {
                    t0[cc] = t[cc];
                    t1[cc] = t[SP + cc];
                    t2[cc] = t[2 * SP + cc];
                }
                float vb0[5], vb1[5];
#pragma unroll
                for (int cc = 0; cc < 5; ++cc) {
                    vb0[cc] = w.z * t0[cc] + w.w * t1[cc];
                    vb1[cc] = w.z * t1[cc] + w.w * t2[cc];
                }
                f4 d0, d1;
                d0.x = w.x * vb0[0] + w.y * vb0[1];
                d0.y = w.x * vb0[1] + w.y * vb0[2];
                d0.z = w.x * vb0[2] + w.y * vb0[3];
                d0.w = w.x * vb0[3] + w.y * vb0[4];
                d1.x = w.x * vb1[0] + w.y * vb1[1];
                d1.y = w.x * vb1[1] + w.y * vb1[2];
                d1.z = w.x * vb1[2] + w.y * vb1[3];
                d1.w = w.x * vb1[3] + w.y * vb1[4];
                a[k][0] += d0; a[k][1] += d1;
            }
            __syncthreads();
        }
    } else {
        // fallback: global clamped gather (correctness path, ~never taken)
        for (int lam = l0; lam < l1; ++lam) {
            const float* __restrict__ img = cb + lam * (HH * WW);
#pragma unroll
            for (int k = 0; k < NK; ++k) {
                const int i_ = k * NLAM + lam;
                const int2 o = po[i_]; const float4 w = pw[i_];
#pragma unroll
                for (int j = 0; j < 2; ++j) {
                    const int iy = y + j + o.y;
                    const int ix = x + o.x;
                    const int cy0 = min(max(iy, 0), HH - 1);
                    const int cy1 = min(max(iy + 1, 0), HH - 1);
                    const float my0 = ((unsigned)iy       < (unsigned)HH) ? w.z : 0.0f;
                    const float my1 = ((unsigned)(iy + 1) < (unsigned)HH) ? w.w : 0.0f;
                    const float* r0p = img + cy0 * WW;
                    const float* r1p = img + cy1 * WW;
                    float rb[5];
#pragma unroll
                    for (int cc = 0; cc < 5; ++cc) {
                        const int cx = min(max(ix + cc, 0), WW - 1);
                        const float m = ((unsigned)(ix + cc) < (unsigned)WW) ? 1.0f : 0.0f;
                        rb[cc] = m * (my0 * r0p[cx] + my1 * r1p[cx]);
                    }
                    f4 d;
                    d.x = w.x * rb[0] + w.y * rb[1];
                    d.y = w.x * rb[1] + w.y * rb[2];
                    d.z = w.x * rb[2] + w.y * rb[3];
                    d.w = w.x * rb[3] + w.y * rb[4];
                    a[k][j] += d;
                }
            }
        }
    }

    if (x < WO) {
        const size_t hw = (size_t)HO * WO;
        float* pa = part + (size_t)c * ACC_N + ((size_t)(b * NK) * HO + y) * WO + x;
#pragma unroll
        for (int k = 0; k < NK; ++k) {
            *(f4a*)(pa + (size_t)k * hw)      = a[k][0];
            *(f4a*)(pa + (size_t)k * hw + WO) = a[k][1];
        }
    }
}

// ---------------------------------------------------------------------------
// Kernel 2: 15x15 PSF correlation, zero-padded "same".
// Sums the S lambda-partials during tile staging (reduce_k folded in).
// psf staged in LDS -> broadcast reads, off the VMEM path.
// Tile 96x32 outputs per block, block (24,8) = 192 thr, 4x4 outputs/thread.
// ---------------------------------------------------------------------------
#define TPX 112
__global__ __launch_bounds__(192) void conv_psf(const float* __restrict__ part,
                                                const float* __restrict__ psf,
                                                float* __restrict__ out, int S) {
    __shared__ float tilec[46][TPX];
    __shared__ float spsf[KS * KS];
    const int bk  = blockIdx.z;               // b*4 + k
    const int gx0 = blockIdx.x * 96 - PADK;
    const int gy0 = blockIdx.y * 32 - PADK;
    const float* __restrict__ ap = part + (size_t)bk * HO * WO;

    const int tid = threadIdx.y * 24 + threadIdx.x;   // 0..191
    for (int i = tid; i < KS * KS; i += 192) spsf[i] = psf[i];
    for (int i = tid; i < 46 * 110; i += 192) {
        int r = i / 110, c = i - r * 110;
        int gy = gy0 + r, gx = gx0 + c;
        float v = 0.f;
        if ((unsigned)gy < (unsigned)HO && (unsigned)gx < (unsigned)WO) {
            const size_t idx = (size_t)gy * WO + gx;
            v = ap[idx];
            for (int cc = 1; cc < S; ++cc) v += ap[(size_t)cc * ACC_N + idx];
        }
        tilec[r][c] = v;
    }
    __syncthreads();

    const int x0 = threadIdx.x * 4;   // 0..92
    const int y0 = threadIdx.y * 4;   // 0..28
    float o[4][4] = {};

    for (int rr = 0; rr < 18; ++rr) {
        const float* rp = &tilec[y0 + rr][x0];
        float row[18];
#pragma unroll
        for (int q = 0; q < 4; ++q) {
            f4a v = *(const f4a*)(rp + 4 * q);
            row[4 * q]     = v.x; row[4 * q + 1] = v.y;
            row[4 * q + 2] = v.z; row[4 * q + 3] = v.w;
        }
        row[16] = rp[16]; row[17] = rp[17];

#pragma unroll
        for (int j = 0; j < 4; ++j) {
            const int ky = rr - j;
            if (ky >= 0 && ky < KS) {
                const float* w = &spsf[ky * KS];
#pragma unroll
                for (int kx = 0; kx < KS; ++kx) {
                    const float wv = w[kx];
#pragma unroll
                    for (int i = 0; i < 4; ++i) o[j][i] += wv * row[kx + i];
                }
            }
        }
    }

    const int xo = blockIdx.x * 96 + x0;
    const int yo = blockIdx.y * 32 + y0;
    float* op = out + ((size_t)bk * HO + yo) * WO + xo;
#pragma unroll
    for (int j = 0; j < 4; ++j) {
        f4a v = { o[j][0], o[j][1], o[j][2], o[j][3] };
        *(f4a*)(op + (size_t)j * WO) = v;
    }
}

// ---------------------------------------------------------------------------
extern "C" void kernel_launch(void* const* d_in, const int* in_sizes, int n_in,
                              void* d_out, int out_size, void* d_ws, size_t ws_size,
                              hipStream_t stream) {
    const float* cube = (const float*)d_in[0];
    const float* dx   = (const float*)d_in[1];
    const float* dy   = (const float*)d_in[2];
    const float* psf  = (const float*)d_in[3];
    float* out = (float*)d_out;

    const size_t ACCB   = ACC_N * sizeof(float);
    const size_t tables = 384 * sizeof(float4) + 384 * sizeof(int2) + sizeof(int4);

    // partials reduced inside conv_psf -> need only S*ACCB + tables
    int S = 1;
    for (int cand : {6, 5, 4, 3, 2}) {
        if (ws_size >= (size_t)cand * ACCB + tables) { S = cand; break; }
    }
    const int chunk = (NLAM + S - 1) / S;

    float* part = (float*)d_ws;
    char*  tb   = (char*)d_ws + (size_t)S * ACCB;
    float4* pw  = (float4*)tb;
    int2*   po  = (int2*)(tb + 384 * sizeof(float4));
    int4*   gmm = (int4*)(tb + 384 * sizeof(float4) + 384 * sizeof(int2));

    params_k<<<1, 384, 0, stream>>>(dx, dy, pw, po, gmm);

    dim3 b1(16, 16);
    dim3 g1((WO + 63) / 64, HO / 32, BB * S);
    shift_accum<<<g1, b1, 0, stream>>>(cube, pw, po, gmm, part, S, chunk);

    dim3 b2(24, 8);
    dim3 g2(WO / 96, HO / 32, BB * NK);
    conv_psf<<<g2, b2, 0, stream>>>(part, psf, out, S);
}

// Round 6
// 255.638 us; speedup vs baseline: 1.8181x; 1.0548x over previous
//
#include <hip/hip_runtime.h>

#define BB 4
#define NLAM 96
#define HH 256
#define WW 256
#define HO 288
#define WO 288
#define NK 4
#define KS 15
#define PADK 7

#define ACC_N ((size_t)BB * NK * HO * WO)   // floats in one partial slice

// shift_accum LDS tile: up to 65 rows x 104 data cols, pitch 105 (odd ->
// stride-4 gathers and row-strided access stay <=4-way on 32 banks).
#define SP 105
#define SROWS 65
#define SQUADS 26          // 26 quads = 104 cols capacity

typedef float f4 __attribute__((ext_vector_type(4), aligned(4)));
typedef float f4a __attribute__((ext_vector_type(4)));  // 16B aligned

// ---------------------------------------------------------------------------
// Kernel 0: per-(k,lam) shift params + offset min/max via shuffle reduction.
// pw = (wx0, wx1, wy0, wy1); po = (ox, oy); gmm = (minox, maxox, minoy, maxoy)
// ---------------------------------------------------------------------------
__global__ __launch_bounds__(384) void params_k(const float* __restrict__ dx,
                                                const float* __restrict__ dy,
                                                float4* __restrict__ pw,
                                                int2* __restrict__ po,
                                                int4* __restrict__ gmm) {
    __shared__ int sox[384], soy[384];
    const int i = threadIdx.x;
    const float sx = -dx[i] - 16.0f;
    const float sy = -dy[i] - 16.0f;
    const float fx = floorf(sx), fy = floorf(sy);
    const int ox = (int)fx, oy = (int)fy;
    po[i] = make_int2(ox, oy);
    pw[i] = make_float4(1.0f - (sx - fx), sx - fx, 1.0f - (sy - fy), sy - fy);
    sox[i] = ox; soy[i] = oy;
    __syncthreads();
    if (i < 64) {
        int mnx = sox[i], mxx = mnx, mny = soy[i], mxy = mny;
        for (int j = i + 64; j < 384; j += 64) {
            mnx = min(mnx, sox[j]); mxx = max(mxx, sox[j]);
            mny = min(mny, soy[j]); mxy = max(mxy, soy[j]);
        }
        for (int m = 32; m; m >>= 1) {
            mnx = min(mnx, __shfl_xor(mnx, m, 64));
            mxx = max(mxx, __shfl_xor(mxx, m, 64));
            mny = min(mny, __shfl_xor(mny, m, 64));
            mxy = max(mxy, __shfl_xor(mxy, m, 64));
        }
        if (i == 0) *gmm = make_int4(mnx, mxx, mny, mxy);
    }
}

// ---------------------------------------------------------------------------
// Kernel 1: shift + accumulate over a lambda chunk; grid.z = BB * S.
// Block (16,16) covers a 64x32 output tile; thread = 4x2 outputs per k.
// Per lambda: stage apron region into LDS (zero-filled OOB), gather 4 k's.
// ---------------------------------------------------------------------------
__global__ __launch_bounds__(256, 4) void shift_accum(
        const float* __restrict__ cube,
        const float4* __restrict__ pw,
        const int2* __restrict__ po,
        const int4* __restrict__ gmm,
        float* __restrict__ part,
        int S, int chunk) {
    __shared__ float tile[SROWS * SP];
    const int zc  = blockIdx.z;
    const int b   = zc / S;
    const int c   = zc - b * S;
    const int tx0 = blockIdx.x * 64;
    const int ty0 = blockIdx.y * 32;
    const int tx  = threadIdx.x, ty = threadIdx.y;
    const int x   = tx0 + tx * 4;
    const int y   = ty0 + ty * 2;
    const int tid = ty * 16 + tx;
    const float* __restrict__ cb = cube + (size_t)b * NLAM * HH * WW;

    const int4 mm = *gmm;   // uniform scalar load
    const int spanX = mm.y - mm.x;
    const int spanY = mm.w - mm.z;
    const bool lds_ok = (spanX <= 32) && (spanY <= 31);   // grid-uniform

    f4 a[NK][2];
#pragma unroll
    for (int k = 0; k < NK; ++k) { a[k][0] = (f4)0.f; a[k][1] = (f4)0.f; }

    const int l0 = min(NLAM, c * chunk);
    const int l1 = min(NLAM, l0 + chunk);

    if (lds_ok) {
        const int row0 = ty0 + mm.z;
        const int col0 = (tx0 + mm.x) & ~3;
        const int R    = spanY + 34;              // staged rows, <= 65
        const int lrb  = ty * 2 - mm.z;           // + o.y = gather row
        const int lcb  = tx * 4 + (tx0 - col0);   // + o.x = gather col

        for (int lam = l0; lam < l1; ++lam) {
            const float* __restrict__ img = cb + lam * (HH * WW);
            // ---- stage R x 104 region, zero-filled outside image ----
            for (int q = tid; q < R * SQUADS; q += 256) {
                const int r  = q / SQUADS;
                const int qi = q - r * SQUADS;
                const int gy = row0 + r;
                const int gc = col0 + qi * 4;
                f4a v = {0.f, 0.f, 0.f, 0.f};
                if ((unsigned)gy < (unsigned)HH) {
                    const float* rp = img + (gy << 8);
                    if ((unsigned)gc <= (unsigned)(WW - 4)) {
                        v = *(const f4a*)(rp + gc);
                    } else {
#pragma unroll
                        for (int e = 0; e < 4; ++e)
                            if ((unsigned)(gc + e) < (unsigned)WW) v[e] = rp[gc + e];
                    }
                }
                const int la = r * SP + qi * 4;
                tile[la]     = v.x; tile[la + 1] = v.y;
                tile[la + 2] = v.z; tile[la + 3] = v.w;
            }
            __syncthreads();
            // ---- gather 4 k's: 3 rows x 5 cols each, 2 output rows ----
#pragma unroll
            for (int k = 0; k < NK; ++k) {
                const int i_ = k * NLAM + lam;
                const int2 o = po[i_]; const float4 w = pw[i_];
                const float* t = &tile[(lrb + o.y) * SP + (lcb + o.x)];
                float t0[5], t1[5], t2[5];
#pragma unroll
                for (int cc = 0; cc < 5; ++cc) {
                    t0[cc] = t[cc];
                    t1[cc] = t[SP + cc];
                    t2[cc] = t[2 * SP + cc];
                }
                float vb0[5], vb1[5];
#pragma unroll
                for (int cc = 0; cc < 5; ++cc) {
                    vb0[cc] = w.z * t0[cc] + w.w * t1[cc];
                    vb1[cc] = w.z * t1[cc] + w.w * t2[cc];
                }
                f4 d0, d1;
                d0.x = w.x * vb0[0] + w.y * vb0[1];
                d0.y = w.x * vb0[1] + w.y * vb0[2];
                d0.z = w.x * vb0[2] + w.y * vb0[3];
                d0.w = w.x * vb0[3] + w.y * vb0[4];
                d1.x = w.x * vb1[0] + w.y * vb1[1];
                d1.y = w.x * vb1[1] + w.y * vb1[2];
                d1.z = w.x * vb1[2] + w.y * vb1[3];
                d1.w = w.x * vb1[3] + w.y * vb1[4];
                a[k][0] += d0; a[k][1] += d1;
            }
            __syncthreads();
        }
    } else {
        // fallback: global clamped gather (correctness path, ~never taken)
        for (int lam = l0; lam < l1; ++lam) {
            const float* __restrict__ img = cb + lam * (HH * WW);
#pragma unroll
            for (int k = 0; k < NK; ++k) {
                const int i_ = k * NLAM + lam;
                const int2 o = po[i_]; const float4 w = pw[i_];
#pragma unroll
                for (int j = 0; j < 2; ++j) {
                    const int iy = y + j + o.y;
                    const int ix = x + o.x;
                    const int cy0 = min(max(iy, 0), HH - 1);
                    const int cy1 = min(max(iy + 1, 0), HH - 1);
                    const float my0 = ((unsigned)iy       < (unsigned)HH) ? w.z : 0.0f;
                    const float my1 = ((unsigned)(iy + 1) < (unsigned)HH) ? w.w : 0.0f;
                    const float* r0p = img + cy0 * WW;
                    const float* r1p = img + cy1 * WW;
                    float rb[5];
#pragma unroll
                    for (int cc = 0; cc < 5; ++cc) {
                        const int cx = min(max(ix + cc, 0), WW - 1);
                        const float m = ((unsigned)(ix + cc) < (unsigned)WW) ? 1.0f : 0.0f;
                        rb[cc] = m * (my0 * r0p[cx] + my1 * r1p[cx]);
                    }
                    f4 d;
                    d.x = w.x * rb[0] + w.y * rb[1];
                    d.y = w.x * rb[1] + w.y * rb[2];
                    d.z = w.x * rb[2] + w.y * rb[3];
                    d.w = w.x * rb[3] + w.y * rb[4];
                    a[k][j] += d;
                }
            }
        }
    }

    if (x < WO) {
        const size_t hw = (size_t)HO * WO;
        float* pa = part + (size_t)c * ACC_N + ((size_t)(b * NK) * HO + y) * WO + x;
#pragma unroll
        for (int k = 0; k < NK; ++k) {
            *(f4a*)(pa + (size_t)k * hw)      = a[k][0];
            *(f4a*)(pa + (size_t)k * hw + WO) = a[k][1];
        }
    }
}

// ---------------------------------------------------------------------------
// Kernel 2: 15x15 PSF correlation, zero-padded "same".
// Compile-time S: the S partial slices are loaded into INDEPENDENT registers
// (unrolled) so the VMEM latencies overlap, instead of a serial dependent
// chain (the round-5 bug: runtime-S loop -> ~S x 600cyc per staged element).
// Tile 96x32 outputs per block, block (24,8) = 192 thr, 4x4 outputs/thread.
// ---------------------------------------------------------------------------
#define TPX 112
template <int S>
__global__ __launch_bounds__(192) void conv_psf(const float* __restrict__ part,
                                                const float* __restrict__ psf,
                                                float* __restrict__ out) {
    __shared__ float tilec[46][TPX];
    __shared__ float spsf[KS * KS];
    const int bk  = blockIdx.z;               // b*4 + k
    const int gx0 = blockIdx.x * 96 - PADK;
    const int gy0 = blockIdx.y * 32 - PADK;
    const float* __restrict__ ap = part + (size_t)bk * HO * WO;

    const int tid = threadIdx.y * 24 + threadIdx.x;   // 0..191
    for (int i = tid; i < KS * KS; i += 192) spsf[i] = psf[i];
    for (int i = tid; i < 46 * 110; i += 192) {
        int r = i / 110, c = i - r * 110;
        int gy = gy0 + r, gx = gx0 + c;
        float v = 0.f;
        if ((unsigned)gy < (unsigned)HO && (unsigned)gx < (unsigned)WO) {
            const size_t idx = (size_t)gy * WO + gx;
            float t[S];
#pragma unroll
            for (int cc = 0; cc < S; ++cc)            // independent loads
                t[cc] = ap[(size_t)cc * ACC_N + idx];
#pragma unroll
            for (int cc = 0; cc < S; ++cc) v += t[cc];
        }
        tilec[r][c] = v;
    }
    __syncthreads();

    const int x0 = threadIdx.x * 4;   // 0..92
    const int y0 = threadIdx.y * 4;   // 0..28
    float o[4][4] = {};

    for (int rr = 0; rr < 18; ++rr) {
        const float* rp = &tilec[y0 + rr][x0];
        float row[18];
#pragma unroll
        for (int q = 0; q < 4; ++q) {
            f4a v = *(const f4a*)(rp + 4 * q);
            row[4 * q]     = v.x; row[4 * q + 1] = v.y;
            row[4 * q + 2] = v.z; row[4 * q + 3] = v.w;
        }
        row[16] = rp[16]; row[17] = rp[17];

#pragma unroll
        for (int j = 0; j < 4; ++j) {
            const int ky = rr - j;
            if (ky >= 0 && ky < KS) {
                const float* w = &spsf[ky * KS];
#pragma unroll
                for (int kx = 0; kx < KS; ++kx) {
                    const float wv = w[kx];
#pragma unroll
                    for (int i = 0; i < 4; ++i) o[j][i] += wv * row[kx + i];
                }
            }
        }
    }

    const int xo = blockIdx.x * 96 + x0;
    const int yo = blockIdx.y * 32 + y0;
    float* op = out + ((size_t)bk * HO + yo) * WO + xo;
#pragma unroll
    for (int j = 0; j < 4; ++j) {
        f4a v = { o[j][0], o[j][1], o[j][2], o[j][3] };
        *(f4a*)(op + (size_t)j * WO) = v;
    }
}

// ---------------------------------------------------------------------------
extern "C" void kernel_launch(void* const* d_in, const int* in_sizes, int n_in,
                              void* d_out, int out_size, void* d_ws, size_t ws_size,
                              hipStream_t stream) {
    const float* cube = (const float*)d_in[0];
    const float* dx   = (const float*)d_in[1];
    const float* dy   = (const float*)d_in[2];
    const float* psf  = (const float*)d_in[3];
    float* out = (float*)d_out;

    const size_t ACCB   = ACC_N * sizeof(float);
    const size_t tables = 384 * sizeof(float4) + 384 * sizeof(int2) + sizeof(int4);

    // partials reduced inside conv_psf -> need only S*ACCB + tables
    int S = 1;
    for (int cand : {8, 6, 5, 4, 3, 2}) {
        if (ws_size >= (size_t)cand * ACCB + tables) { S = cand; break; }
    }
    const int chunk = (NLAM + S - 1) / S;

    float* part = (float*)d_ws;
    char*  tb   = (char*)d_ws + (size_t)S * ACCB;
    float4* pw  = (float4*)tb;
    int2*   po  = (int2*)(tb + 384 * sizeof(float4));
    int4*   gmm = (int4*)(tb + 384 * sizeof(float4) + 384 * sizeof(int2));

    params_k<<<1, 384, 0, stream>>>(dx, dy, pw, po, gmm);

    dim3 b1(16, 16);
    dim3 g1((WO + 63) / 64, HO / 32, BB * S);
    shift_accum<<<g1, b1, 0, stream>>>(cube, pw, po, gmm, part, S, chunk);

    dim3 b2(24, 8);
    dim3 g2(WO / 96, HO / 32, BB * NK);
    switch (S) {
        case 8: conv_psf<8><<<g2, b2, 0, stream>>>(part, psf, out); break;
        case 6: conv_psf<6><<<g2, b2, 0, stream>>>(part, psf, out); break;
        case 5: conv_psf<5><<<g2, b2, 0, stream>>>(part, psf, out); break;
        case 4: conv_psf<4><<<g2, b2, 0, stream>>>(part, psf, out); break;
        case 3: conv_psf<3><<<g2, b2, 0, stream>>>(part, psf, out); break;
        case 2: conv_psf<2><<<g2, b2, 0, stream>>>(part, psf, out); break;
        default: conv_psf<1><<<g2, b2, 0, stream>>>(part, psf, out); break;
    }
}

// Round 7
// 226.688 us; speedup vs baseline: 2.0502x; 1.1277x over previous
//
#include <hip/hip_runtime.h>

#define BB 4
#define NLAM 96
#define HH 256
#define WW 256
#define HO 288
#define WO 288
#define NK 4
#define KS 15
#define PADK 7

#define ACC_N ((size_t)BB * NK * HO * WO)   // floats in one partial slice

// shift_accum LDS tile: 65 rows x 104 data cols, pitch 105 (odd).
#define SP 105
#define TILE_N (65 * SP)     // 6825
#define SDUMMY TILE_N        // dummy quad slot (4 floats spare)
#define NQ 7                 // staging slots per thread (7*256 >= 65*26)

typedef float f4 __attribute__((ext_vector_type(4), aligned(4)));
typedef float f4a __attribute__((ext_vector_type(4)));  // 16B aligned

// ---------------------------------------------------------------------------
// Kernel 0: per-(k,lam) shift params + offset min/max via shuffle reduction.
// ---------------------------------------------------------------------------
__global__ __launch_bounds__(384) void params_k(const float* __restrict__ dx,
                                                const float* __restrict__ dy,
                                                float4* __restrict__ pw,
                                                int2* __restrict__ po,
                                                int4* __restrict__ gmm) {
    __shared__ int sox[384], soy[384];
    const int i = threadIdx.x;
    const float sx = -dx[i] - 16.0f;
    const float sy = -dy[i] - 16.0f;
    const float fx = floorf(sx), fy = floorf(sy);
    const int ox = (int)fx, oy = (int)fy;
    po[i] = make_int2(ox, oy);
    pw[i] = make_float4(1.0f - (sx - fx), sx - fx, 1.0f - (sy - fy), sy - fy);
    sox[i] = ox; soy[i] = oy;
    __syncthreads();
    if (i < 64) {
        int mnx = sox[i], mxx = mnx, mny = soy[i], mxy = mny;
        for (int j = i + 64; j < 384; j += 64) {
            mnx = min(mnx, sox[j]); mxx = max(mxx, sox[j]);
            mny = min(mny, soy[j]); mxy = max(mxy, soy[j]);
        }
        for (int m = 32; m; m >>= 1) {
            mnx = min(mnx, __shfl_xor(mnx, m, 64));
            mxx = max(mxx, __shfl_xor(mxx, m, 64));
            mny = min(mny, __shfl_xor(mny, m, 64));
            mxy = max(mxy, __shfl_xor(mxy, m, 64));
        }
        if (i == 0) *gmm = make_int4(mnx, mxx, mny, mxy);
    }
}

// ---------------------------------------------------------------------------
// Kernel 1: shift + accumulate over a lambda chunk; grid.z = BB * S.
// Block (16,16) covers 64x32 tile; thread = 4x2 outputs per k.
// Staging is precomputed per-slot (lambda-invariant): clamped global offset,
// LDS address, quad mask; per lambda it is load+mask+write, branchless except
// a rare edge-quad scalar path (execz-skipped on interior blocks).
// ---------------------------------------------------------------------------
__global__ __launch_bounds__(256, 4) void shift_accum(
        const float* __restrict__ cube,
        const float4* __restrict__ pw,
        const int2* __restrict__ po,
        const int4* __restrict__ gmm,
        float* __restrict__ part,
        int S, int chunk) {
    __shared__ float tile[TILE_N + 8];
    const int zc  = blockIdx.z;
    const int b   = zc / S;
    const int c   = zc - b * S;
    const int tx0 = blockIdx.x * 64;
    const int ty0 = blockIdx.y * 32;
    const int tx  = threadIdx.x, ty = threadIdx.y;
    const int x   = tx0 + tx * 4;
    const int y   = ty0 + ty * 2;
    const int tid = ty * 16 + tx;
    const float* __restrict__ cb = cube + (size_t)b * NLAM * HH * WW;

    const int4 mm = *gmm;   // uniform scalar load
    const int spanX = mm.y - mm.x;
    const int spanY = mm.w - mm.z;
    const bool lds_ok = (spanX <= 32) && (spanY <= 31);   // grid-uniform

    f4a a[NK][2];
#pragma unroll
    for (int k = 0; k < NK; ++k) { a[k][0] = (f4a)0.f; a[k][1] = (f4a)0.f; }

    const int l0 = min(NLAM, c * chunk);
    const int l1 = min(NLAM, l0 + chunk);

    if (lds_ok) {
        const int row0 = ty0 + mm.z;
        const int col0 = (tx0 + mm.x) & ~3;
        const int R    = spanY + 34;              // staged rows, <= 65
        const int tb0  = (ty * 2 - mm.z) * SP + (tx * 4 + (tx0 - col0));

        // ---- lambda-invariant staging precompute ----
        int  goffB[NQ];    // byte offset into one cube slice (clamped, safe)
        int  waddr[NQ];    // LDS float index for the f4 path (dummy if partial)
        float mf[NQ];      // quad-uniform validity multiplier
        int  pf = 0;       // partial-quad flags
#pragma unroll
        for (int s = 0; s < NQ; ++s) {
            const int q  = tid + s * 256;
            const bool inR = q < R * 26;
            const int r  = q / 26;
            const int qi = q - r * 26;
            const int gy = row0 + r;
            const int gc = col0 + qi * 4;
            const bool rowOK = (unsigned)gy < (unsigned)HH;
            const bool fullQ = rowOK && gc >= 0 && gc <= WW - 4;
            const bool partQ = inR && rowOK && !fullQ && (gc + 3 >= 0) && (gc < WW);
            const int gyc = min(max(gy, 0), HH - 1);
            const int gcc = min(max(gc, 0), WW - 4);
            goffB[s] = (gyc * WW + gcc) * 4;
            mf[s]    = (inR && fullQ) ? 1.0f : 0.0f;
            waddr[s] = (inR && !partQ) ? (r * SP + qi * 4) : SDUMMY;
            if (partQ) pf |= 1 << s;
        }

        // ---- pre-zero tile (permanent zeros for OOB + dummy) ----
        for (int i = tid; i < TILE_N + 8; i += 256) tile[i] = 0.0f;
        __syncthreads();

        for (int lam = l0; lam < l1; ++lam) {
            const char* __restrict__ ib = (const char*)(cb + lam * (HH * WW));
            // ---- stage: branchless masked quads ----
#pragma unroll
            for (int s = 0; s < NQ; ++s) {
                f4a v = *(const f4a*)(ib + goffB[s]);
                const float m = mf[s];
                const int wa = waddr[s];
                tile[wa]     = v.x * m;
                tile[wa + 1] = v.y * m;
                tile[wa + 2] = v.z * m;
                tile[wa + 3] = v.w * m;
            }
            // ---- rare edge quads: scalar path ----
            if (pf) {
#pragma unroll
                for (int s = 0; s < NQ; ++s) {
                    if (pf & (1 << s)) {
                        const int q  = tid + s * 256;
                        const int r  = q / 26;
                        const int qi = q - r * 26;
                        const int gy = row0 + r;
                        const int gc = col0 + qi * 4;
                        const float* rp = (const float*)ib + gy * WW;
                        const int la = r * SP + qi * 4;
#pragma unroll
                        for (int e = 0; e < 4; ++e)
                            if ((unsigned)(gc + e) < (unsigned)WW)
                                tile[la + e] = rp[gc + e];
                    }
                }
            }
            __syncthreads();
            // ---- gather 4 k's: 3 rows x 5 cols each, 2 output rows ----
#pragma unroll
            for (int k = 0; k < NK; ++k) {
                const int i_ = k * NLAM + lam;
                const int2 o = po[i_]; const float4 w = pw[i_];
                const float* t = tile + tb0 + o.y * SP + o.x;
                float t0[5], t1[5], t2[5];
#pragma unroll
                for (int cc = 0; cc < 5; ++cc) {
                    t0[cc] = t[cc];
                    t1[cc] = t[SP + cc];
                    t2[cc] = t[2 * SP + cc];
                }
                f4a r0 = {t0[0], t0[1], t0[2], t0[3]};
                f4a r1 = {t1[0], t1[1], t1[2], t1[3]};
                f4a r2 = {t2[0], t2[1], t2[2], t2[3]};
                f4a vb0 = w.z * r0 + w.w * r1;
                f4a vb1 = w.z * r1 + w.w * r2;
                const float e0 = w.z * t0[4] + w.w * t1[4];
                const float e1 = w.z * t1[4] + w.w * t2[4];
                f4a s0 = {vb0.y, vb0.z, vb0.w, e0};
                f4a s1 = {vb1.y, vb1.z, vb1.w, e1};
                a[k][0] += w.x * vb0 + w.y * s0;
                a[k][1] += w.x * vb1 + w.y * s1;
            }
            __syncthreads();
        }
    } else {
        // fallback: global clamped gather (correctness path, ~never taken)
        for (int lam = l0; lam < l1; ++lam) {
            const float* __restrict__ img = cb + lam * (HH * WW);
#pragma unroll
            for (int k = 0; k < NK; ++k) {
                const int i_ = k * NLAM + lam;
                const int2 o = po[i_]; const float4 w = pw[i_];
#pragma unroll
                for (int j = 0; j < 2; ++j) {
                    const int iy = y + j + o.y;
                    const int ix = x + o.x;
                    const int cy0 = min(max(iy, 0), HH - 1);
                    const int cy1 = min(max(iy + 1, 0), HH - 1);
                    const float my0 = ((unsigned)iy       < (unsigned)HH) ? w.z : 0.0f;
                    const float my1 = ((unsigned)(iy + 1) < (unsigned)HH) ? w.w : 0.0f;
                    const float* r0p = img + cy0 * WW;
                    const float* r1p = img + cy1 * WW;
                    float rb[5];
#pragma unroll
                    for (int cc = 0; cc < 5; ++cc) {
                        const int cx = min(max(ix + cc, 0), WW - 1);
                        const float m = ((unsigned)(ix + cc) < (unsigned)WW) ? 1.0f : 0.0f;
                        rb[cc] = m * (my0 * r0p[cx] + my1 * r1p[cx]);
                    }
                    f4a d;
                    d.x = w.x * rb[0] + w.y * rb[1];
                    d.y = w.x * rb[1] + w.y * rb[2];
                    d.z = w.x * rb[2] + w.y * rb[3];
                    d.w = w.x * rb[3] + w.y * rb[4];
                    a[k][j] += d;
                }
            }
        }
    }

    if (x < WO) {
        const size_t hw = (size_t)HO * WO;
        float* pa = part + (size_t)c * ACC_N + ((size_t)(b * NK) * HO + y) * WO + x;
#pragma unroll
        for (int k = 0; k < NK; ++k) {
            *(f4a*)(pa + (size_t)k * hw)      = a[k][0];
            *(f4a*)(pa + (size_t)k * hw + WO) = a[k][1];
        }
    }
}

// ---------------------------------------------------------------------------
// Kernel 2: 15x15 PSF correlation, zero-padded "same", summing S partials.
// Tile 96x16 outputs, block (24,8)=192 thr, 4x2 outputs/thread.
// Staging: quad loads of all S slices (independent), per-element f4 mask
// (part buffer is ours + 64B front pad, so unaligned/edge quads are safe).
// PSF in LDS padded to 16/row -> b128 row loads, cur/prev register reuse.
// ---------------------------------------------------------------------------
#define CPX 112
#define CROWS 30
#define CTILE_N (CROWS * CPX)   // 3360
#define CDUMMY CTILE_N
#define NQC 5

template <int S>
__global__ __launch_bounds__(192) void conv_psf(const float* __restrict__ part,
                                                const float* __restrict__ psf,
                                                float* __restrict__ out) {
    __shared__ float tilec[CTILE_N + 8];
    __shared__ float spsf[KS][16];
    const int bk  = blockIdx.z;               // b*4 + k
    const int gx0 = blockIdx.x * 96 - PADK;
    const int gy0 = blockIdx.y * 16 - PADK;
    const float* __restrict__ ap = part + (size_t)bk * HO * WO;

    const int tid = threadIdx.y * 24 + threadIdx.x;   // 0..191
    for (int i = tid; i < KS * 16; i += 192) {
        const int r = i >> 4, cc2 = i & 15;
        spsf[r][cc2] = (cc2 < KS) ? psf[r * KS + cc2] : 0.0f;
    }

    // staging precompute
    int goffB[NQC], laddr[NQC];
    f4a cmask[NQC];
#pragma unroll
    for (int s = 0; s < NQC; ++s) {
        const int q  = tid + s * 192;
        const bool inR = q < CROWS * 28;
        const int r  = q / 28;
        const int qi = q - r * 28;
        const int gy = gy0 + r;
        const int gx = gx0 + qi * 4;
        const bool rowOK = (unsigned)gy < (unsigned)HO;
        const int gyc = min(max(gy, 0), HO - 1);
        goffB[s] = (gyc * WO + gx) * 4;           // may be slightly OOB: padded
        laddr[s] = inR ? (r * CPX + qi * 4) : CDUMMY;
        f4a m;
#pragma unroll
        for (int e = 0; e < 4; ++e)
            m[e] = (inR && rowOK && (unsigned)(gx + e) < (unsigned)WO) ? 1.0f : 0.0f;
        cmask[s] = m;
    }

#pragma unroll
    for (int s = 0; s < NQC; ++s) {
        const char* base = (const char*)ap + goffB[s];
        f4a acc = (f4a)0.f;
#pragma unroll
        for (int cc = 0; cc < S; ++cc) {
            f4 v = *(const f4*)(base + (size_t)cc * (ACC_N * 4));
            acc += (f4a)v;
        }
        acc *= cmask[s];
        const int la = laddr[s];
        tilec[la] = acc.x; tilec[la + 1] = acc.y;
        tilec[la + 2] = acc.z; tilec[la + 3] = acc.w;
    }
    __syncthreads();

    const int x0 = threadIdx.x * 4;   // 0..92
    const int y0 = threadIdx.y * 2;   // 0..14
    f4a o0 = (f4a)0.f, o1 = (f4a)0.f;
    f4a prev0, prev1, prev2, prev3;

#pragma unroll
    for (int rr = 0; rr < 16; ++rr) {
        const float* rp = &tilec[(y0 + rr) * CPX + x0];
        float row[18];
#pragma unroll
        for (int q = 0; q < 4; ++q) {
            f4a v = *(const f4a*)(rp + 4 * q);
            row[4 * q]     = v.x; row[4 * q + 1] = v.y;
            row[4 * q + 2] = v.z; row[4 * q + 3] = v.w;
        }
        row[16] = rp[16]; row[17] = rp[17];

        f4a c0, c1, c2, c3;
        if (rr < 15) {
            c0 = *(const f4a*)&spsf[rr][0];
            c1 = *(const f4a*)&spsf[rr][4];
            c2 = *(const f4a*)&spsf[rr][8];
            c3 = *(const f4a*)&spsf[rr][12];
        }
        if (rr < 15) {   // j=0: ky=rr, weights cur
#pragma unroll
            for (int kx = 0; kx < KS; ++kx) {
                const float wv = (kx < 4) ? c0[kx] : (kx < 8) ? c1[kx - 4]
                               : (kx < 12) ? c2[kx - 8] : c3[kx - 12];
                f4a rv = {row[kx], row[kx + 1], row[kx + 2], row[kx + 3]};
                o0 += wv * rv;
            }
        }
        if (rr >= 1) {   // j=1: ky=rr-1, weights prev
#pragma unroll
            for (int kx = 0; kx < KS; ++kx) {
                const float wv = (kx < 4) ? prev0[kx] : (kx < 8) ? prev1[kx - 4]
                               : (kx < 12) ? prev2[kx - 8] : prev3[kx - 12];
                f4a rv = {row[kx], row[kx + 1], row[kx + 2], row[kx + 3]};
                o1 += wv * rv;
            }
        }
        prev0 = c0; prev1 = c1; prev2 = c2; prev3 = c3;
    }

    const int xo = blockIdx.x * 96 + x0;
    const int yo = blockIdx.y * 16 + y0;
    float* op = out + ((size_t)bk * HO + yo) * WO + xo;
    *(f4a*)op        = o0;
    *(f4a*)(op + WO) = o1;
}

// ---------------------------------------------------------------------------
extern "C" void kernel_launch(void* const* d_in, const int* in_sizes, int n_in,
                              void* d_out, int out_size, void* d_ws, size_t ws_size,
                              hipStream_t stream) {
    const float* cube = (const float*)d_in[0];
    const float* dx   = (const float*)d_in[1];
    const float* dy   = (const float*)d_in[2];
    const float* psf  = (const float*)d_in[3];
    float* out = (float*)d_out;

    const size_t ACCB   = ACC_N * sizeof(float);
    const size_t tables = 384 * sizeof(float4) + 384 * sizeof(int2) + sizeof(int4);

    int S = 1;
    for (int cand : {12, 8, 6, 4, 3, 2}) {
        if (ws_size >= 64 + (size_t)cand * ACCB + tables + 4096) { S = cand; break; }
    }
    const int chunk = (NLAM + S - 1) / S;

    float* part = (float*)((char*)d_ws + 64);   // 64B front pad for edge quads
    char*  tb   = (char*)part + (size_t)S * ACCB;
    float4* pw  = (float4*)tb;
    int2*   po  = (int2*)(tb + 384 * sizeof(float4));
    int4*   gmm = (int4*)(tb + 384 * sizeof(float4) + 384 * sizeof(int2));

    params_k<<<1, 384, 0, stream>>>(dx, dy, pw, po, gmm);

    dim3 b1(16, 16);
    dim3 g1((WO + 63) / 64, HO / 32, BB * S);
    shift_accum<<<g1, b1, 0, stream>>>(cube, pw, po, gmm, part, S, chunk);

    dim3 b2(24, 8);
    dim3 g2(WO / 96, HO / 16, BB * NK);
    switch (S) {
        case 12: conv_psf<12><<<g2, b2, 0, stream>>>(part, psf, out); break;
        case 8:  conv_psf<8><<<g2, b2, 0, stream>>>(part, psf, out); break;
        case 6:  conv_psf<6><<<g2, b2, 0, stream>>>(part, psf, out); break;
        case 4:  conv_psf<4><<<g2, b2, 0, stream>>>(part, psf, out); break;
        case 3:  conv_psf<3><<<g2, b2, 0, stream>>>(part, psf, out); break;
        case 2:  conv_psf<2><<<g2, b2, 0, stream>>>(part, psf, out); break;
        default: conv_psf<1><<<g2, b2, 0, stream>>>(part, psf, out); break;
    }
}